// Round 1
// baseline (1210.377 us; speedup 1.0000x reference)
//
#include <hip/hip_runtime.h>

#define NN 100000
#define NE 1600000
#define NG 4096
#define HID 128
#define ODIM 64
#define BN_EPS 1e-5f

// ---------------- degree histogram (dst) ----------------
__global__ __launch_bounds__(256) void k_deg(const int* __restrict__ ei, int* __restrict__ deg) {
  int e = blockIdx.x * 256 + threadIdx.x;
  if (e < NE) atomicAdd(&deg[ei[NE + e]], 1);
}

__global__ __launch_bounds__(256) void k_dinv(const int* __restrict__ deg, float* __restrict__ dinv) {
  int i = blockIdx.x * 256 + threadIdx.x;
  if (i < NN) dinv[i] = rsqrtf((float)deg[i] + 1.0f);
}

// ---------------- exclusive scan of deg -> CSR offsets (single block) ----------------
__global__ __launch_bounds__(1024) void k_scan(const int* __restrict__ deg, int* __restrict__ off) {
  __shared__ int part[1024];
  int t = threadIdx.x;
  const int CH = (NN + 1023) / 1024;  // 98
  int lo = min(t * CH, NN), hi = min(lo + CH, NN);
  int s = 0;
  for (int i = lo; i < hi; ++i) s += deg[i];
  part[t] = s;
  __syncthreads();
  for (int d = 1; d < 1024; d <<= 1) {
    int v = 0;
    if (t >= d) v = part[t - d];
    __syncthreads();
    part[t] += v;
    __syncthreads();
  }
  int run = (t == 0) ? 0 : part[t - 1];
  for (int i = lo; i < hi; ++i) { off[i] = run; run += deg[i]; }
  if (t == 1023) off[NN] = part[1023];
}

// ---------------- CSR fill: edge ids bucketed by dst, with precomputed norm ----------------
__global__ __launch_bounds__(256) void k_fill(const int* __restrict__ ei, const int* __restrict__ off,
                                              int* __restrict__ cur, const float* __restrict__ dinv,
                                              int* __restrict__ csrc, float* __restrict__ cnrm) {
  int e = blockIdx.x * 256 + threadIdx.x;
  if (e >= NE) return;
  int s = ei[e], d = ei[NE + e];
  int pos = off[d] + atomicAdd(&cur[d], 1);
  csrc[pos] = s;
  cnrm[pos] = dinv[s] * dinv[d];
}

// ---------------- graph start offsets via binary search over sorted batch ----------------
__global__ __launch_bounds__(256) void k_goff(const int* __restrict__ batch, int* __restrict__ goff) {
  int g = blockIdx.x * 256 + threadIdx.x;
  if (g > NG) return;
  int lo = 0, hi = NN;
  while (lo < hi) { int mid = (lo + hi) >> 1; if (batch[mid] < g) lo = mid + 1; else hi = mid; }
  goff[g] = lo;
}

// ---------------- H = f(A) @ W ; f = identity or relu(a*scale+shift) fused on load ----------------
// block = 256 threads, tile 64 rows x 128 cols, K streamed in chunks of 16
__global__ __launch_bounds__(256) void k_gemm(const float* __restrict__ A, const float* __restrict__ W,
                                              const float* __restrict__ scale, const float* __restrict__ shift,
                                              float* __restrict__ H) {
  __shared__ float As[16][68];   // [k][row], padded: fp4-aligned rows, no write conflicts
  __shared__ float Ws[16][128];  // [k][col]
  int t = threadIdx.x;
  int row0 = blockIdx.x * 64;
  int rg = t >> 4, cg = t & 15;          // compute mapping: 4 rows x 8 cols per thread
  int lr = t >> 2, kq = (t & 3) << 2;    // A-load mapping
  int wk = t >> 4, wc = (t & 15) << 3;   // W-load mapping
  float acc[4][8];
#pragma unroll
  for (int r = 0; r < 4; ++r)
#pragma unroll
    for (int c = 0; c < 8; ++c) acc[r][c] = 0.f;

  int arow = row0 + lr;
  bool aok = arow < NN;
  for (int k0 = 0; k0 < HID; k0 += 16) {
    float4 av = make_float4(0.f, 0.f, 0.f, 0.f);
    if (aok) av = *(const float4*)(A + (size_t)arow * HID + k0 + kq);
    if (scale) {  // fused BN+ReLU on the input features (garbage on pad rows is store-guarded)
      float4 sc = *(const float4*)(scale + k0 + kq);
      float4 sh = *(const float4*)(shift + k0 + kq);
      av.x = fmaxf(fmaf(av.x, sc.x, sh.x), 0.f);
      av.y = fmaxf(fmaf(av.y, sc.y, sh.y), 0.f);
      av.z = fmaxf(fmaf(av.z, sc.z, sh.z), 0.f);
      av.w = fmaxf(fmaf(av.w, sc.w, sh.w), 0.f);
    }
    As[kq + 0][lr] = av.x; As[kq + 1][lr] = av.y; As[kq + 2][lr] = av.z; As[kq + 3][lr] = av.w;
    float4 w0 = *(const float4*)(W + (size_t)(k0 + wk) * HID + wc);
    float4 w1 = *(const float4*)(W + (size_t)(k0 + wk) * HID + wc + 4);
    *(float4*)&Ws[wk][wc] = w0;
    *(float4*)&Ws[wk][wc + 4] = w1;
    __syncthreads();
#pragma unroll
    for (int k = 0; k < 16; ++k) {
      float4 a  = *(const float4*)&As[k][rg << 2];
      float4 b0 = *(const float4*)&Ws[k][cg << 3];
      float4 b1 = *(const float4*)&Ws[k][(cg << 3) + 4];
      float ar[4] = {a.x, a.y, a.z, a.w};
      float bc[8] = {b0.x, b0.y, b0.z, b0.w, b1.x, b1.y, b1.z, b1.w};
#pragma unroll
      for (int r = 0; r < 4; ++r)
#pragma unroll
        for (int c = 0; c < 8; ++c) acc[r][c] = fmaf(ar[r], bc[c], acc[r][c]);
    }
    __syncthreads();
  }
#pragma unroll
  for (int r = 0; r < 4; ++r) {
    int grow = row0 + (rg << 2) + r;
    if (grow < NN) {
      float4 o0 = make_float4(acc[r][0], acc[r][1], acc[r][2], acc[r][3]);
      float4 o1 = make_float4(acc[r][4], acc[r][5], acc[r][6], acc[r][7]);
      *(float4*)(H + (size_t)grow * HID + (cg << 3)) = o0;
      *(float4*)(H + (size_t)grow * HID + (cg << 3) + 4) = o1;
    }
  }
}

// ---------------- pull aggregation: wave = node, lane = 2 feats, no atomics ----------------
__global__ __launch_bounds__(256) void k_agg(const float* __restrict__ h, const int* __restrict__ off,
                                             const int* __restrict__ csrc, const float* __restrict__ cnrm,
                                             const float* __restrict__ dinv, float* __restrict__ agg) {
  int node = (int)((blockIdx.x * 256 + threadIdx.x) >> 6);
  int lane = threadIdx.x & 63;
  if (node >= NN) return;
  int beg = off[node], end = off[node + 1];
  float di = dinv[node];
  float2 self = ((const float2*)(h + (size_t)node * HID))[lane];
  float d2 = di * di;
  float2 acc;
  acc.x = self.x * d2;
  acc.y = self.y * d2;
  for (int e = beg; e < end; ++e) {
    int s = csrc[e];
    float w = cnrm[e];
    float2 v = ((const float2*)(h + (size_t)s * HID))[lane];
    acc.x = fmaf(v.x, w, acc.x);
    acc.y = fmaf(v.y, w, acc.y);
  }
  ((float2*)(agg + (size_t)node * HID))[lane] = acc;
}

// ---------------- BN statistics: per-feature sum & sumsq ----------------
__global__ __launch_bounds__(256) void k_bnstats(const float* __restrict__ X, float* __restrict__ buf) {
  __shared__ float ls[256], lss[256];
  int t = threadIdx.x;
  int col = t & 127, half = t >> 7;
  int rbeg = blockIdx.x * 256, rend = min(rbeg + 256, NN);
  float s = 0.f, ss = 0.f;
  for (int r = rbeg + half; r < rend; r += 2) {
    float v = X[(size_t)r * HID + col];
    s += v; ss = fmaf(v, v, ss);
  }
  ls[t] = s; lss[t] = ss;
  __syncthreads();
  if (t < 128) {
    s = ls[t] + ls[t + 128];
    ss = lss[t] + lss[t + 128];
    atomicAdd(&buf[col], s);
    atomicAdd(&buf[HID + col], ss);
  }
}

// buf: [sum(128), sumsq(128)] -> in place [scale(128), shift(128)]
__global__ void k_bnfinal(float* __restrict__ buf, const float* __restrict__ g, const float* __restrict__ be) {
  int j = threadIdx.x;
  const float invN = 1.0f / (float)NN;
  float mu = buf[j] * invN;
  float var = buf[HID + j] * invN - mu * mu;  // biased var, matches torch/jax training BN
  float sc = g[j] * rsqrtf(var + BN_EPS);
  buf[j] = sc;
  buf[HID + j] = be[j] - mu * sc;
}

// ---------------- mean pool per graph (applies layer-3 BN+ReLU on the fly) ----------------
__global__ __launch_bounds__(256) void k_pool(const float* __restrict__ agg, const float* __restrict__ bn,
                                              const int* __restrict__ goff, float* __restrict__ pooled) {
  int g = (int)((blockIdx.x * 256 + threadIdx.x) >> 6);
  int lane = threadIdx.x & 63;
  if (g >= NG) return;
  int beg = goff[g], end = goff[g + 1];
  float2 sc = ((const float2*)bn)[lane];
  float2 sh = ((const float2*)(bn + HID))[lane];
  float2 acc = {0.f, 0.f};
  for (int r = beg; r < end; ++r) {
    float2 v = ((const float2*)(agg + (size_t)r * HID))[lane];
    acc.x += fmaxf(fmaf(v.x, sc.x, sh.x), 0.f);
    acc.y += fmaxf(fmaf(v.y, sc.y, sh.y), 0.f);
  }
  float inv = 1.0f / fmaxf((float)(end - beg), 1.0f);
  acc.x *= inv; acc.y *= inv;
  ((float2*)(pooled + (size_t)g * HID))[lane] = acc;
}

// ---------------- final FC: out[g][c] = pooled[g,:] @ fcW[:,c] + fcb[c] ----------------
__global__ __launch_bounds__(256) void k_fc(const float* __restrict__ pooled, const float* __restrict__ fcW,
                                            const float* __restrict__ fcb, float* __restrict__ out) {
  int t = threadIdx.x;
  int c = t & 63;
  int g = blockIdx.x * 4 + (t >> 6);
  if (g >= NG) return;
  const float* p = pooled + (size_t)g * HID;
  float acc = fcb[c];
#pragma unroll 8
  for (int k = 0; k < HID; ++k) acc = fmaf(p[k], fcW[(size_t)k * ODIM + c], acc);
  out[(size_t)g * ODIM + c] = acc;
}

extern "C" void kernel_launch(void* const* d_in, const int* in_sizes, int n_in,
                              void* d_out, int out_size, void* d_ws, size_t ws_size,
                              hipStream_t stream) {
  const float* x     = (const float*)d_in[0];
  const int*   ei    = (const int*)d_in[1];
  const int*   batch = (const int*)d_in[2];
  const float* W1    = (const float*)d_in[3];
  // b1/b2/b3 (d_in[4,8,12]) are skipped: a per-feature bias cancels exactly in the following BN
  const float* g1    = (const float*)d_in[5];
  const float* be1   = (const float*)d_in[6];
  const float* W2    = (const float*)d_in[7];
  const float* g2    = (const float*)d_in[9];
  const float* be2   = (const float*)d_in[10];
  const float* W3    = (const float*)d_in[11];
  const float* g3    = (const float*)d_in[13];
  const float* be3   = (const float*)d_in[14];
  const float* fcW   = (const float*)d_in[15];
  const float* fcb   = (const float*)d_in[16];
  float* out = (float*)d_out;

  // workspace bump allocator, 256B aligned. Zero-init region first.
  char* p = (char*)d_ws;
  auto alloc = [&](size_t bytes) { char* r = p; p += (bytes + 255) & ~(size_t)255; return r; };
  int*   deg    = (int*)alloc((size_t)NN * 4);
  int*   cur    = (int*)alloc((size_t)NN * 4);
  float* bnb    = (float*)alloc(3 * 256 * 4);          // 3 layers x [sum|sumsq] -> [scale|shift]
  size_t zbytes = (size_t)(p - (char*)d_ws);
  int*   off    = (int*)alloc((size_t)(NN + 1) * 4);
  float* dinv   = (float*)alloc((size_t)NN * 4);
  int*   csrc   = (int*)alloc((size_t)NE * 4);
  float* cnrm   = (float*)alloc((size_t)NE * 4);
  int*   goff   = (int*)alloc((size_t)(NG + 1) * 4);
  float* h      = (float*)alloc((size_t)NN * HID * 4);
  float* agg    = (float*)alloc((size_t)NN * HID * 4);
  float* pooled = (float*)alloc((size_t)NG * HID * 4);

  hipMemsetAsync(d_ws, 0, zbytes, stream);

  const int EB = NE / 256;             // 6250
  const int NB = (NN + 255) / 256;     // 391
  const int GB = (NN + 63) / 64;       // 1563 gemm row-blocks
  const int AGB = NN / 4;              // 25000 agg blocks (4 waves each)

  k_deg<<<EB, 256, 0, stream>>>(ei, deg);
  k_dinv<<<NB, 256, 0, stream>>>(deg, dinv);
  k_scan<<<1, 1024, 0, stream>>>(deg, off);
  k_fill<<<EB, 256, 0, stream>>>(ei, off, cur, dinv, csrc, cnrm);
  k_goff<<<(NG + 1 + 255) / 256, 256, 0, stream>>>(batch, goff);

  // layer 1
  k_gemm<<<GB, 256, 0, stream>>>(x, W1, nullptr, nullptr, h);
  k_agg<<<AGB, 256, 0, stream>>>(h, off, csrc, cnrm, dinv, agg);
  k_bnstats<<<NB, 256, 0, stream>>>(agg, bnb);
  k_bnfinal<<<1, 128, 0, stream>>>(bnb, g1, be1);
  // layer 2 (BN+ReLU of layer 1 fused into A-load)
  k_gemm<<<GB, 256, 0, stream>>>(agg, W2, bnb, bnb + HID, h);
  k_agg<<<AGB, 256, 0, stream>>>(h, off, csrc, cnrm, dinv, agg);
  k_bnstats<<<NB, 256, 0, stream>>>(agg, bnb + 256);
  k_bnfinal<<<1, 128, 0, stream>>>(bnb + 256, g2, be2);
  // layer 3
  k_gemm<<<GB, 256, 0, stream>>>(agg, W3, bnb + 256, bnb + 256 + HID, h);
  k_agg<<<AGB, 256, 0, stream>>>(h, off, csrc, cnrm, dinv, agg);
  k_bnstats<<<NB, 256, 0, stream>>>(agg, bnb + 512);
  k_bnfinal<<<1, 128, 0, stream>>>(bnb + 512, g3, be3);
  // pool (layer-3 BN+ReLU fused) + FC
  k_pool<<<(NG * 64) / 256, 256, 0, stream>>>(agg, bnb + 512, goff, pooled);
  k_fc<<<NG / 4, 256, 0, stream>>>(pooled, fcW, fcb, out);
}

// Round 2
// 948.159 us; speedup vs baseline: 1.2766x; 1.2766x over previous
//
#include <hip/hip_runtime.h>

#define NN 100000
#define NE 1600000
#define NG 4096
#define HID 128
#define ODIM 64
#define BN_EPS 1e-5f

typedef unsigned int u32;
typedef unsigned short u16;

// bf16 pack (RNE) of two floats -> uint (lo = a, hi = b)
__device__ inline u32 pack_bf16(float a, float b) {
  u32 ua = __float_as_uint(a), ub = __float_as_uint(b);
  ua += 0x7fffu + ((ua >> 16) & 1u);
  ub += 0x7fffu + ((ub >> 16) & 1u);
  return (ua >> 16) | (ub & 0xffff0000u);
}
__device__ inline float bf_lo(u32 u) { return __uint_as_float(u << 16); }
__device__ inline float bf_hi(u32 u) { return __uint_as_float(u & 0xffff0000u); }

// ---------------- degree histogram (dst) ----------------
__global__ __launch_bounds__(256) void k_deg(const int* __restrict__ ei, int* __restrict__ deg) {
  int e = blockIdx.x * 256 + threadIdx.x;
  if (e < NE) atomicAdd(&deg[ei[NE + e]], 1);
}

__global__ __launch_bounds__(256) void k_dinv(const int* __restrict__ deg, float* __restrict__ dinv) {
  int i = blockIdx.x * 256 + threadIdx.x;
  if (i < NN) dinv[i] = rsqrtf((float)deg[i] + 1.0f);
}

// ---------------- exclusive scan of deg -> CSR offsets (single block) ----------------
__global__ __launch_bounds__(1024) void k_scan(const int* __restrict__ deg, int* __restrict__ off) {
  __shared__ int part[1024];
  int t = threadIdx.x;
  const int CH = (NN + 1023) / 1024;  // 98
  int lo = min(t * CH, NN), hi = min(lo + CH, NN);
  int s = 0;
  for (int i = lo; i < hi; ++i) s += deg[i];
  part[t] = s;
  __syncthreads();
  for (int d = 1; d < 1024; d <<= 1) {
    int v = 0;
    if (t >= d) v = part[t - d];
    __syncthreads();
    part[t] += v;
    __syncthreads();
  }
  int run = (t == 0) ? 0 : part[t - 1];
  for (int i = lo; i < hi; ++i) { off[i] = run; run += deg[i]; }
  if (t == 1023) off[NN] = part[1023];
}

// ---------------- CSR fill: (src, norm) packed per edge, bucketed by dst ----------------
__global__ __launch_bounds__(256) void k_fill(const int* __restrict__ ei, const int* __restrict__ off,
                                              int* __restrict__ cur, const float* __restrict__ dinv,
                                              uint2* __restrict__ ced) {
  int e = blockIdx.x * 256 + threadIdx.x;
  if (e >= NE) return;
  int s = ei[e], d = ei[NE + e];
  int pos = off[d] + atomicAdd(&cur[d], 1);
  ced[pos] = make_uint2((u32)s, __float_as_uint(dinv[s] * dinv[d]));
}

// ---------------- graph start offsets via binary search over sorted batch ----------------
__global__ __launch_bounds__(256) void k_goff(const int* __restrict__ batch, int* __restrict__ goff) {
  int g = blockIdx.x * 256 + threadIdx.x;
  if (g > NG) return;
  int lo = 0, hi = NN;
  while (lo < hi) { int mid = (lo + hi) >> 1; if (batch[mid] < g) lo = mid + 1; else hi = mid; }
  goff[g] = lo;
}

// ---------------- H = f(A) @ W, H stored bf16 ; f = identity or relu(a*scale+shift) ----------------
// block = 256 threads, tile 64 rows x 128 cols, K streamed in chunks of 16
__global__ __launch_bounds__(256) void k_gemm(const float* __restrict__ A, const float* __restrict__ W,
                                              const float* __restrict__ scale, const float* __restrict__ shift,
                                              u16* __restrict__ H) {
  __shared__ float As[16][68];
  __shared__ float Ws[16][128];
  int t = threadIdx.x;
  int row0 = blockIdx.x * 64;
  int rg = t >> 4, cg = t & 15;          // compute: 4 rows x 8 cols per thread
  int lr = t >> 2, kq = (t & 3) << 2;    // A-load mapping
  int wk = t >> 4, wc = (t & 15) << 3;   // W-load mapping
  float acc[4][8];
#pragma unroll
  for (int r = 0; r < 4; ++r)
#pragma unroll
    for (int c = 0; c < 8; ++c) acc[r][c] = 0.f;

  int arow = row0 + lr;
  bool aok = arow < NN;
  for (int k0 = 0; k0 < HID; k0 += 16) {
    float4 av = make_float4(0.f, 0.f, 0.f, 0.f);
    if (aok) av = *(const float4*)(A + (size_t)arow * HID + k0 + kq);
    if (scale) {
      float4 sc = *(const float4*)(scale + k0 + kq);
      float4 sh = *(const float4*)(shift + k0 + kq);
      av.x = fmaxf(fmaf(av.x, sc.x, sh.x), 0.f);
      av.y = fmaxf(fmaf(av.y, sc.y, sh.y), 0.f);
      av.z = fmaxf(fmaf(av.z, sc.z, sh.z), 0.f);
      av.w = fmaxf(fmaf(av.w, sc.w, sh.w), 0.f);
    }
    As[kq + 0][lr] = av.x; As[kq + 1][lr] = av.y; As[kq + 2][lr] = av.z; As[kq + 3][lr] = av.w;
    float4 w0 = *(const float4*)(W + (size_t)(k0 + wk) * HID + wc);
    float4 w1 = *(const float4*)(W + (size_t)(k0 + wk) * HID + wc + 4);
    *(float4*)&Ws[wk][wc] = w0;
    *(float4*)&Ws[wk][wc + 4] = w1;
    __syncthreads();
#pragma unroll
    for (int k = 0; k < 16; ++k) {
      float4 a  = *(const float4*)&As[k][rg << 2];
      float4 b0 = *(const float4*)&Ws[k][cg << 3];
      float4 b1 = *(const float4*)&Ws[k][(cg << 3) + 4];
      float ar[4] = {a.x, a.y, a.z, a.w};
      float bc[8] = {b0.x, b0.y, b0.z, b0.w, b1.x, b1.y, b1.z, b1.w};
#pragma unroll
      for (int r = 0; r < 4; ++r)
#pragma unroll
        for (int c = 0; c < 8; ++c) acc[r][c] = fmaf(ar[r], bc[c], acc[r][c]);
    }
    __syncthreads();
  }
#pragma unroll
  for (int r = 0; r < 4; ++r) {
    int grow = row0 + (rg << 2) + r;
    if (grow < NN) {
      uint4 o;
      o.x = pack_bf16(acc[r][0], acc[r][1]);
      o.y = pack_bf16(acc[r][2], acc[r][3]);
      o.z = pack_bf16(acc[r][4], acc[r][5]);
      o.w = pack_bf16(acc[r][6], acc[r][7]);
      *(uint4*)((u32*)(H + (size_t)grow * HID) + (cg << 2)) = o;
    }
  }
}

// ---------------- pull aggregation: wave = node, lane = 2 feats (bf16 rows), no atomics ----------------
__global__ __launch_bounds__(256) void k_agg(const u16* __restrict__ h, const int* __restrict__ off,
                                             const uint2* __restrict__ ced,
                                             const float* __restrict__ dinv, float* __restrict__ agg) {
  int node = (int)((blockIdx.x * 256 + threadIdx.x) >> 6);
  int lane = threadIdx.x & 63;
  if (node >= NN) return;
  int beg = off[node], end = off[node + 1];
  float di = dinv[node];
  u32 us = ((const u32*)(h + (size_t)node * HID))[lane];
  float d2 = di * di;
  float ax = bf_lo(us) * d2;
  float ay = bf_hi(us) * d2;
  int e = beg;
  for (; e + 4 <= end; e += 4) {
    uint2 c0 = ced[e], c1 = ced[e + 1], c2 = ced[e + 2], c3 = ced[e + 3];
    u32 v0 = ((const u32*)(h + (size_t)c0.x * HID))[lane];
    u32 v1 = ((const u32*)(h + (size_t)c1.x * HID))[lane];
    u32 v2 = ((const u32*)(h + (size_t)c2.x * HID))[lane];
    u32 v3 = ((const u32*)(h + (size_t)c3.x * HID))[lane];
    float w0 = __uint_as_float(c0.y), w1 = __uint_as_float(c1.y);
    float w2 = __uint_as_float(c2.y), w3 = __uint_as_float(c3.y);
    ax = fmaf(bf_lo(v0), w0, ax); ay = fmaf(bf_hi(v0), w0, ay);
    ax = fmaf(bf_lo(v1), w1, ax); ay = fmaf(bf_hi(v1), w1, ay);
    ax = fmaf(bf_lo(v2), w2, ax); ay = fmaf(bf_hi(v2), w2, ay);
    ax = fmaf(bf_lo(v3), w3, ax); ay = fmaf(bf_hi(v3), w3, ay);
  }
  for (; e < end; ++e) {
    uint2 c = ced[e];
    u32 v = ((const u32*)(h + (size_t)c.x * HID))[lane];
    float w = __uint_as_float(c.y);
    ax = fmaf(bf_lo(v), w, ax);
    ay = fmaf(bf_hi(v), w, ay);
  }
  float2 o; o.x = ax; o.y = ay;
  ((float2*)(agg + (size_t)node * HID))[lane] = o;
}

// ---------------- BN statistics: per-feature sum & sumsq ----------------
__global__ __launch_bounds__(256) void k_bnstats(const float* __restrict__ X, float* __restrict__ buf) {
  __shared__ float ls[256], lss[256];
  int t = threadIdx.x;
  int col = t & 127, half = t >> 7;
  int rbeg = blockIdx.x * 256, rend = min(rbeg + 256, NN);
  float s = 0.f, ss = 0.f;
  for (int r = rbeg + half; r < rend; r += 2) {
    float v = X[(size_t)r * HID + col];
    s += v; ss = fmaf(v, v, ss);
  }
  ls[t] = s; lss[t] = ss;
  __syncthreads();
  if (t < 128) {
    s = ls[t] + ls[t + 128];
    ss = lss[t] + lss[t + 128];
    atomicAdd(&buf[col], s);
    atomicAdd(&buf[HID + col], ss);
  }
}

// buf: [sum(128), sumsq(128)] -> in place [scale(128), shift(128)]
__global__ void k_bnfinal(float* __restrict__ buf, const float* __restrict__ g, const float* __restrict__ be) {
  int j = threadIdx.x;
  const float invN = 1.0f / (float)NN;
  float mu = buf[j] * invN;
  float var = buf[HID + j] * invN - mu * mu;
  float sc = g[j] * rsqrtf(var + BN_EPS);
  buf[j] = sc;
  buf[HID + j] = be[j] - mu * sc;
}

// ---------------- mean pool per graph (applies layer-3 BN+ReLU on the fly) ----------------
__global__ __launch_bounds__(256) void k_pool(const float* __restrict__ agg, const float* __restrict__ bn,
                                              const int* __restrict__ goff, float* __restrict__ pooled) {
  int g = (int)((blockIdx.x * 256 + threadIdx.x) >> 6);
  int lane = threadIdx.x & 63;
  if (g >= NG) return;
  int beg = goff[g], end = goff[g + 1];
  float2 sc = ((const float2*)bn)[lane];
  float2 sh = ((const float2*)(bn + HID))[lane];
  float2 acc; acc.x = 0.f; acc.y = 0.f;
  for (int r = beg; r < end; ++r) {
    float2 v = ((const float2*)(agg + (size_t)r * HID))[lane];
    acc.x += fmaxf(fmaf(v.x, sc.x, sh.x), 0.f);
    acc.y += fmaxf(fmaf(v.y, sc.y, sh.y), 0.f);
  }
  float inv = 1.0f / fmaxf((float)(end - beg), 1.0f);
  acc.x *= inv; acc.y *= inv;
  ((float2*)(pooled + (size_t)g * HID))[lane] = acc;
}

// ---------------- final FC ----------------
__global__ __launch_bounds__(256) void k_fc(const float* __restrict__ pooled, const float* __restrict__ fcW,
                                            const float* __restrict__ fcb, float* __restrict__ out) {
  int t = threadIdx.x;
  int c = t & 63;
  int g = blockIdx.x * 4 + (t >> 6);
  if (g >= NG) return;
  const float* p = pooled + (size_t)g * HID;
  float acc = fcb[c];
#pragma unroll 8
  for (int k = 0; k < HID; ++k) acc = fmaf(p[k], fcW[(size_t)k * ODIM + c], acc);
  out[(size_t)g * ODIM + c] = acc;
}

extern "C" void kernel_launch(void* const* d_in, const int* in_sizes, int n_in,
                              void* d_out, int out_size, void* d_ws, size_t ws_size,
                              hipStream_t stream) {
  const float* x     = (const float*)d_in[0];
  const int*   ei    = (const int*)d_in[1];
  const int*   batch = (const int*)d_in[2];
  const float* W1    = (const float*)d_in[3];
  // b1/b2/b3 (d_in[4,8,12]) skipped: per-feature bias cancels exactly in the following BN
  const float* g1    = (const float*)d_in[5];
  const float* be1   = (const float*)d_in[6];
  const float* W2    = (const float*)d_in[7];
  const float* g2    = (const float*)d_in[9];
  const float* be2   = (const float*)d_in[10];
  const float* W3    = (const float*)d_in[11];
  const float* g3    = (const float*)d_in[13];
  const float* be3   = (const float*)d_in[14];
  const float* fcW   = (const float*)d_in[15];
  const float* fcb   = (const float*)d_in[16];
  float* out = (float*)d_out;

  char* p = (char*)d_ws;
  auto alloc = [&](size_t bytes) { char* r = p; p += (bytes + 255) & ~(size_t)255; return r; };
  int*   deg    = (int*)alloc((size_t)NN * 4);
  int*   cur    = (int*)alloc((size_t)NN * 4);
  float* bnb    = (float*)alloc(3 * 256 * 4);
  size_t zbytes = (size_t)(p - (char*)d_ws);
  int*   off    = (int*)alloc((size_t)(NN + 1) * 4);
  float* dinv   = (float*)alloc((size_t)NN * 4);
  uint2* ced    = (uint2*)alloc((size_t)NE * 8);
  int*   goff   = (int*)alloc((size_t)(NG + 1) * 4);
  u16*   h      = (u16*)alloc((size_t)NN * HID * 2);
  float* agg    = (float*)alloc((size_t)NN * HID * 4);
  float* pooled = (float*)alloc((size_t)NG * HID * 4);

  hipMemsetAsync(d_ws, 0, zbytes, stream);

  const int EB = NE / 256;             // 6250
  const int NB = (NN + 255) / 256;     // 391
  const int GB = (NN + 63) / 64;       // 1563
  const int AGB = NN / 4;              // 25000

  k_deg<<<EB, 256, 0, stream>>>(ei, deg);
  k_dinv<<<NB, 256, 0, stream>>>(deg, dinv);
  k_scan<<<1, 1024, 0, stream>>>(deg, off);
  k_fill<<<EB, 256, 0, stream>>>(ei, off, cur, dinv, ced);
  k_goff<<<(NG + 1 + 255) / 256, 256, 0, stream>>>(batch, goff);

  // layer 1
  k_gemm<<<GB, 256, 0, stream>>>(x, W1, nullptr, nullptr, h);
  k_agg<<<AGB, 256, 0, stream>>>(h, off, ced, dinv, agg);
  k_bnstats<<<NB, 256, 0, stream>>>(agg, bnb);
  k_bnfinal<<<1, 128, 0, stream>>>(bnb, g1, be1);
  // layer 2
  k_gemm<<<GB, 256, 0, stream>>>(agg, W2, bnb, bnb + HID, h);
  k_agg<<<AGB, 256, 0, stream>>>(h, off, ced, dinv, agg);
  k_bnstats<<<NB, 256, 0, stream>>>(agg, bnb + 256);
  k_bnfinal<<<1, 128, 0, stream>>>(bnb + 256, g2, be2);
  // layer 3
  k_gemm<<<GB, 256, 0, stream>>>(agg, W3, bnb + 256, bnb + 256 + HID, h);
  k_agg<<<AGB, 256, 0, stream>>>(h, off, ced, dinv, agg);
  k_bnstats<<<NB, 256, 0, stream>>>(agg, bnb + 512);
  k_bnfinal<<<1, 128, 0, stream>>>(bnb + 512, g3, be3);
  // pool + FC
  k_pool<<<(NG * 64) / 256, 256, 0, stream>>>(agg, bnb + 512, goff, pooled);
  k_fc<<<NG / 4, 256, 0, stream>>>(pooled, fcW, fcb, out);
}

// Round 3
// 800.296 us; speedup vs baseline: 1.5124x; 1.1848x over previous
//
#include <hip/hip_runtime.h>

#define NN 100000
#define NE 1600000
#define NG 4096
#define HID 128
#define ODIM 64
#define BN_EPS 1e-5f
#define NB_SCAN 391  // ceil(NN/256)

typedef unsigned int u32;
typedef unsigned short u16;

// bf16 pack (RNE) of two floats -> uint (lo = a, hi = b)
__device__ inline u32 pack_bf16(float a, float b) {
  u32 ua = __float_as_uint(a), ub = __float_as_uint(b);
  ua += 0x7fffu + ((ua >> 16) & 1u);
  ub += 0x7fffu + ((ub >> 16) & 1u);
  return (ua >> 16) | (ub & 0xffff0000u);
}
__device__ inline float bf_lo(u32 u) { return __uint_as_float(u << 16); }
__device__ inline float bf_hi(u32 u) { return __uint_as_float(u & 0xffff0000u); }

// ---------------- degree histogram (dst) ----------------
__global__ __launch_bounds__(256) void k_deg(const int* __restrict__ ei, int* __restrict__ deg) {
  int e = blockIdx.x * 256 + threadIdx.x;
  if (e < NE) atomicAdd(&deg[ei[NE + e]], 1);
}

__global__ __launch_bounds__(256) void k_dinv(const int* __restrict__ deg, float* __restrict__ dinv) {
  int i = blockIdx.x * 256 + threadIdx.x;
  if (i < NN) dinv[i] = rsqrtf((float)deg[i] + 1.0f);
}

// ---------------- hierarchical scan: stage 1, per-block sums ----------------
__global__ __launch_bounds__(256) void k_scan1(const int* __restrict__ deg, int* __restrict__ bsum) {
  __shared__ int ls[256];
  int t = threadIdx.x;
  int i = blockIdx.x * 256 + t;
  ls[t] = (i < NN) ? deg[i] : 0;
  __syncthreads();
  for (int d = 128; d > 0; d >>= 1) {
    if (t < d) ls[t] += ls[t + d];
    __syncthreads();
  }
  if (t == 0) bsum[blockIdx.x] = ls[0];
}

// ---------------- stage 2: exclusive scan of 391 block sums (single small block) ----------------
__global__ __launch_bounds__(512) void k_scan2(int* __restrict__ bsum, int* __restrict__ off) {
  __shared__ int ls[512];
  int t = threadIdx.x;
  ls[t] = (t < NB_SCAN) ? bsum[t] : 0;
  __syncthreads();
  for (int d = 1; d < 512; d <<= 1) {
    int v = 0;
    if (t >= d) v = ls[t - d];
    __syncthreads();
    ls[t] += v;
    __syncthreads();
  }
  // exclusive: bsum[t] = sum of blocks < t
  if (t < NB_SCAN) bsum[t] = (t == 0) ? 0 : ls[t - 1];
  if (t == 511) off[NN] = ls[NB_SCAN - 1];
}

// ---------------- stage 3: in-block exclusive scan + block offset ----------------
__global__ __launch_bounds__(256) void k_scan3(const int* __restrict__ deg, const int* __restrict__ bsum,
                                               int* __restrict__ off) {
  __shared__ int ls[256];
  int t = threadIdx.x;
  int i = blockIdx.x * 256 + t;
  int v = (i < NN) ? deg[i] : 0;
  ls[t] = v;
  __syncthreads();
  for (int d = 1; d < 256; d <<= 1) {
    int u = 0;
    if (t >= d) u = ls[t - d];
    __syncthreads();
    ls[t] += u;
    __syncthreads();
  }
  if (i < NN) off[i] = bsum[blockIdx.x] + ls[t] - v;  // exclusive
}

// ---------------- CSR fill: (src, norm) packed per edge, bucketed by dst ----------------
__global__ __launch_bounds__(256) void k_fill(const int* __restrict__ ei, const int* __restrict__ off,
                                              int* __restrict__ cur, const float* __restrict__ dinv,
                                              uint2* __restrict__ ced) {
  int e = blockIdx.x * 256 + threadIdx.x;
  if (e >= NE) return;
  int s = ei[e], d = ei[NE + e];
  int pos = off[d] + atomicAdd(&cur[d], 1);
  ced[pos] = make_uint2((u32)s, __float_as_uint(dinv[s] * dinv[d]));
}

// ---------------- graph start offsets via binary search over sorted batch ----------------
__global__ __launch_bounds__(256) void k_goff(const int* __restrict__ batch, int* __restrict__ goff) {
  int g = blockIdx.x * 256 + threadIdx.x;
  if (g > NG) return;
  int lo = 0, hi = NN;
  while (lo < hi) { int mid = (lo + hi) >> 1; if (batch[mid] < g) lo = mid + 1; else hi = mid; }
  goff[g] = lo;
}

// ---------------- H = f(A) @ W, H stored bf16 ; f = identity or relu(a*scale+shift) ----------------
__global__ __launch_bounds__(256) void k_gemm(const float* __restrict__ A, const float* __restrict__ W,
                                              const float* __restrict__ scale, const float* __restrict__ shift,
                                              u16* __restrict__ H) {
  __shared__ float As[16][68];
  __shared__ float Ws[16][128];
  int t = threadIdx.x;
  int row0 = blockIdx.x * 64;
  int rg = t >> 4, cg = t & 15;
  int lr = t >> 2, kq = (t & 3) << 2;
  int wk = t >> 4, wc = (t & 15) << 3;
  float acc[4][8];
#pragma unroll
  for (int r = 0; r < 4; ++r)
#pragma unroll
    for (int c = 0; c < 8; ++c) acc[r][c] = 0.f;

  int arow = row0 + lr;
  bool aok = arow < NN;
  for (int k0 = 0; k0 < HID; k0 += 16) {
    float4 av = make_float4(0.f, 0.f, 0.f, 0.f);
    if (aok) av = *(const float4*)(A + (size_t)arow * HID + k0 + kq);
    if (scale) {
      float4 sc = *(const float4*)(scale + k0 + kq);
      float4 sh = *(const float4*)(shift + k0 + kq);
      av.x = fmaxf(fmaf(av.x, sc.x, sh.x), 0.f);
      av.y = fmaxf(fmaf(av.y, sc.y, sh.y), 0.f);
      av.z = fmaxf(fmaf(av.z, sc.z, sh.z), 0.f);
      av.w = fmaxf(fmaf(av.w, sc.w, sh.w), 0.f);
    }
    As[kq + 0][lr] = av.x; As[kq + 1][lr] = av.y; As[kq + 2][lr] = av.z; As[kq + 3][lr] = av.w;
    float4 w0 = *(const float4*)(W + (size_t)(k0 + wk) * HID + wc);
    float4 w1 = *(const float4*)(W + (size_t)(k0 + wk) * HID + wc + 4);
    *(float4*)&Ws[wk][wc] = w0;
    *(float4*)&Ws[wk][wc + 4] = w1;
    __syncthreads();
#pragma unroll
    for (int k = 0; k < 16; ++k) {
      float4 a  = *(const float4*)&As[k][rg << 2];
      float4 b0 = *(const float4*)&Ws[k][cg << 3];
      float4 b1 = *(const float4*)&Ws[k][(cg << 3) + 4];
      float ar[4] = {a.x, a.y, a.z, a.w};
      float bc[8] = {b0.x, b0.y, b0.z, b0.w, b1.x, b1.y, b1.z, b1.w};
#pragma unroll
      for (int r = 0; r < 4; ++r)
#pragma unroll
        for (int c = 0; c < 8; ++c) acc[r][c] = fmaf(ar[r], bc[c], acc[r][c]);
    }
    __syncthreads();
  }
#pragma unroll
  for (int r = 0; r < 4; ++r) {
    int grow = row0 + (rg << 2) + r;
    if (grow < NN) {
      uint4 o;
      o.x = pack_bf16(acc[r][0], acc[r][1]);
      o.y = pack_bf16(acc[r][2], acc[r][3]);
      o.z = pack_bf16(acc[r][4], acc[r][5]);
      o.w = pack_bf16(acc[r][6], acc[r][7]);
      *(uint4*)((u32*)(H + (size_t)grow * HID) + (cg << 2)) = o;
    }
  }
}

// ---------------- pull aggregation: wave = node, lane = 2 feats (bf16 rows), no atomics ----------------
__global__ __launch_bounds__(256) void k_agg(const u16* __restrict__ h, const int* __restrict__ off,
                                             const uint2* __restrict__ ced,
                                             const float* __restrict__ dinv, float* __restrict__ agg) {
  int node = (int)((blockIdx.x * 256 + threadIdx.x) >> 6);
  int lane = threadIdx.x & 63;
  if (node >= NN) return;
  int beg = off[node], end = off[node + 1];
  float di = dinv[node];
  u32 us = ((const u32*)(h + (size_t)node * HID))[lane];
  float d2 = di * di;
  float ax = bf_lo(us) * d2;
  float ay = bf_hi(us) * d2;
  int e = beg;
  for (; e + 4 <= end; e += 4) {
    uint2 c0 = ced[e], c1 = ced[e + 1], c2 = ced[e + 2], c3 = ced[e + 3];
    u32 v0 = ((const u32*)(h + (size_t)c0.x * HID))[lane];
    u32 v1 = ((const u32*)(h + (size_t)c1.x * HID))[lane];
    u32 v2 = ((const u32*)(h + (size_t)c2.x * HID))[lane];
    u32 v3 = ((const u32*)(h + (size_t)c3.x * HID))[lane];
    float w0 = __uint_as_float(c0.y), w1 = __uint_as_float(c1.y);
    float w2 = __uint_as_float(c2.y), w3 = __uint_as_float(c3.y);
    ax = fmaf(bf_lo(v0), w0, ax); ay = fmaf(bf_hi(v0), w0, ay);
    ax = fmaf(bf_lo(v1), w1, ax); ay = fmaf(bf_hi(v1), w1, ay);
    ax = fmaf(bf_lo(v2), w2, ax); ay = fmaf(bf_hi(v2), w2, ay);
    ax = fmaf(bf_lo(v3), w3, ax); ay = fmaf(bf_hi(v3), w3, ay);
  }
  for (; e < end; ++e) {
    uint2 c = ced[e];
    u32 v = ((const u32*)(h + (size_t)c.x * HID))[lane];
    float w = __uint_as_float(c.y);
    ax = fmaf(bf_lo(v), w, ax);
    ay = fmaf(bf_hi(v), w, ay);
  }
  float2 o; o.x = ax; o.y = ay;
  ((float2*)(agg + (size_t)node * HID))[lane] = o;
}

// ---------------- BN statistics: per-feature sum & sumsq ----------------
__global__ __launch_bounds__(256) void k_bnstats(const float* __restrict__ X, float* __restrict__ buf) {
  __shared__ float ls[256], lss[256];
  int t = threadIdx.x;
  int col = t & 127, half = t >> 7;
  int rbeg = blockIdx.x * 256, rend = min(rbeg + 256, NN);
  float s = 0.f, ss = 0.f;
  for (int r = rbeg + half; r < rend; r += 2) {
    float v = X[(size_t)r * HID + col];
    s += v; ss = fmaf(v, v, ss);
  }
  ls[t] = s; lss[t] = ss;
  __syncthreads();
  if (t < 128) {
    s = ls[t] + ls[t + 128];
    ss = lss[t] + lss[t + 128];
    atomicAdd(&buf[col], s);
    atomicAdd(&buf[HID + col], ss);
  }
}

// buf: [sum(128), sumsq(128)] -> in place [scale(128), shift(128)]
__global__ void k_bnfinal(float* __restrict__ buf, const float* __restrict__ g, const float* __restrict__ be) {
  int j = threadIdx.x;
  const float invN = 1.0f / (float)NN;
  float mu = buf[j] * invN;
  float var = buf[HID + j] * invN - mu * mu;
  float sc = g[j] * rsqrtf(var + BN_EPS);
  buf[j] = sc;
  buf[HID + j] = be[j] - mu * sc;
}

// ---------------- mean pool per graph (applies layer-3 BN+ReLU on the fly) ----------------
__global__ __launch_bounds__(256) void k_pool(const float* __restrict__ agg, const float* __restrict__ bn,
                                              const int* __restrict__ goff, float* __restrict__ pooled) {
  int g = (int)((blockIdx.x * 256 + threadIdx.x) >> 6);
  int lane = threadIdx.x & 63;
  if (g >= NG) return;
  int beg = goff[g], end = goff[g + 1];
  float2 sc = ((const float2*)bn)[lane];
  float2 sh = ((const float2*)(bn + HID))[lane];
  float2 acc; acc.x = 0.f; acc.y = 0.f;
  for (int r = beg; r < end; ++r) {
    float2 v = ((const float2*)(agg + (size_t)r * HID))[lane];
    acc.x += fmaxf(fmaf(v.x, sc.x, sh.x), 0.f);
    acc.y += fmaxf(fmaf(v.y, sc.y, sh.y), 0.f);
  }
  float inv = 1.0f / fmaxf((float)(end - beg), 1.0f);
  acc.x *= inv; acc.y *= inv;
  ((float2*)(pooled + (size_t)g * HID))[lane] = acc;
}

// ---------------- final FC ----------------
__global__ __launch_bounds__(256) void k_fc(const float* __restrict__ pooled, const float* __restrict__ fcW,
                                            const float* __restrict__ fcb, float* __restrict__ out) {
  int t = threadIdx.x;
  int c = t & 63;
  int g = blockIdx.x * 4 + (t >> 6);
  if (g >= NG) return;
  const float* p = pooled + (size_t)g * HID;
  float acc = fcb[c];
#pragma unroll 8
  for (int k = 0; k < HID; ++k) acc = fmaf(p[k], fcW[(size_t)k * ODIM + c], acc);
  out[(size_t)g * ODIM + c] = acc;
}

extern "C" void kernel_launch(void* const* d_in, const int* in_sizes, int n_in,
                              void* d_out, int out_size, void* d_ws, size_t ws_size,
                              hipStream_t stream) {
  const float* x     = (const float*)d_in[0];
  const int*   ei    = (const int*)d_in[1];
  const int*   batch = (const int*)d_in[2];
  const float* W1    = (const float*)d_in[3];
  // b1/b2/b3 (d_in[4,8,12]) skipped: per-feature bias cancels exactly in the following BN
  const float* g1    = (const float*)d_in[5];
  const float* be1   = (const float*)d_in[6];
  const float* W2    = (const float*)d_in[7];
  const float* g2    = (const float*)d_in[9];
  const float* be2   = (const float*)d_in[10];
  const float* W3    = (const float*)d_in[11];
  const float* g3    = (const float*)d_in[13];
  const float* be3   = (const float*)d_in[14];
  const float* fcW   = (const float*)d_in[15];
  const float* fcb   = (const float*)d_in[16];
  float* out = (float*)d_out;

  char* p = (char*)d_ws;
  auto alloc = [&](size_t bytes) { char* r = p; p += (bytes + 255) & ~(size_t)255; return r; };
  int*   deg    = (int*)alloc((size_t)NN * 4);
  int*   cur    = (int*)alloc((size_t)NN * 4);
  float* bnb    = (float*)alloc(3 * 256 * 4);
  size_t zbytes = (size_t)(p - (char*)d_ws);
  int*   off    = (int*)alloc((size_t)(NN + 1) * 4);
  int*   bsum   = (int*)alloc((size_t)NB_SCAN * 4);
  float* dinv   = (float*)alloc((size_t)NN * 4);
  uint2* ced    = (uint2*)alloc((size_t)NE * 8);
  int*   goff   = (int*)alloc((size_t)(NG + 1) * 4);
  u16*   h      = (u16*)alloc((size_t)NN * HID * 2);
  float* agg    = (float*)alloc((size_t)NN * HID * 4);
  float* pooled = (float*)alloc((size_t)NG * HID * 4);

  hipMemsetAsync(d_ws, 0, zbytes, stream);

  const int EB = NE / 256;             // 6250
  const int NB = (NN + 255) / 256;     // 391
  const int GB = (NN + 63) / 64;       // 1563
  const int AGB = NN / 4;              // 25000

  k_deg<<<EB, 256, 0, stream>>>(ei, deg);
  k_dinv<<<NB, 256, 0, stream>>>(deg, dinv);
  k_scan1<<<NB_SCAN, 256, 0, stream>>>(deg, bsum);
  k_scan2<<<1, 512, 0, stream>>>(bsum, off);
  k_scan3<<<NB_SCAN, 256, 0, stream>>>(deg, bsum, off);
  k_fill<<<EB, 256, 0, stream>>>(ei, off, cur, dinv, ced);
  k_goff<<<(NG + 1 + 255) / 256, 256, 0, stream>>>(batch, goff);

  // layer 1
  k_gemm<<<GB, 256, 0, stream>>>(x, W1, nullptr, nullptr, h);
  k_agg<<<AGB, 256, 0, stream>>>(h, off, ced, dinv, agg);
  k_bnstats<<<NB, 256, 0, stream>>>(agg, bnb);
  k_bnfinal<<<1, 128, 0, stream>>>(bnb, g1, be1);
  // layer 2
  k_gemm<<<GB, 256, 0, stream>>>(agg, W2, bnb, bnb + HID, h);
  k_agg<<<AGB, 256, 0, stream>>>(h, off, ced, dinv, agg);
  k_bnstats<<<NB, 256, 0, stream>>>(agg, bnb + 256);
  k_bnfinal<<<1, 128, 0, stream>>>(bnb + 256, g2, be2);
  // layer 3
  k_gemm<<<GB, 256, 0, stream>>>(agg, W3, bnb + 256, bnb + 256 + HID, h);
  k_agg<<<AGB, 256, 0, stream>>>(h, off, ced, dinv, agg);
  k_bnstats<<<NB, 256, 0, stream>>>(agg, bnb + 512);
  k_bnfinal<<<1, 128, 0, stream>>>(bnb + 512, g3, be3);
  // pool + FC
  k_pool<<<(NG * 64) / 256, 256, 0, stream>>>(agg, bnb + 512, goff, pooled);
  k_fc<<<NG / 4, 256, 0, stream>>>(pooled, fcW, fcb, out);
}

// Round 4
// 724.427 us; speedup vs baseline: 1.6708x; 1.1047x over previous
//
#include <hip/hip_runtime.h>

#define NN 100000
#define NE 1600000
#define NG 4096
#define HID 128
#define ODIM 64
#define BN_EPS 1e-5f
#define NB_SCAN 391  // ceil(NN/256)

typedef unsigned int u32;
typedef unsigned short u16;
typedef short short8 __attribute__((ext_vector_type(8)));
typedef float f32x4 __attribute__((ext_vector_type(4)));

// bf16 pack (RNE) of two floats -> uint (lo = a, hi = b)
__device__ inline u32 pack_bf16(float a, float b) {
  u32 ua = __float_as_uint(a), ub = __float_as_uint(b);
  ua += 0x7fffu + ((ua >> 16) & 1u);
  ub += 0x7fffu + ((ub >> 16) & 1u);
  return (ua >> 16) | (ub & 0xffff0000u);
}
__device__ inline u16 bf16_of(float v) {
  u32 ua = __float_as_uint(v);
  ua += 0x7fffu + ((ua >> 16) & 1u);
  return (u16)(ua >> 16);
}
__device__ inline float bf_lo(u32 u) { return __uint_as_float(u << 16); }
__device__ inline float bf_hi(u32 u) { return __uint_as_float(u & 0xffff0000u); }

// ---------------- degree histogram (dst) ----------------
__global__ __launch_bounds__(256) void k_deg(const int* __restrict__ ei, int* __restrict__ deg) {
  int e = blockIdx.x * 256 + threadIdx.x;
  if (e < NE) atomicAdd(&deg[ei[NE + e]], 1);
}

__global__ __launch_bounds__(256) void k_dinv(const int* __restrict__ deg, float* __restrict__ dinv) {
  int i = blockIdx.x * 256 + threadIdx.x;
  if (i < NN) dinv[i] = rsqrtf((float)deg[i] + 1.0f);
}

// ---------------- hierarchical scan ----------------
__global__ __launch_bounds__(256) void k_scan1(const int* __restrict__ deg, int* __restrict__ bsum) {
  __shared__ int ls[256];
  int t = threadIdx.x;
  int i = blockIdx.x * 256 + t;
  ls[t] = (i < NN) ? deg[i] : 0;
  __syncthreads();
  for (int d = 128; d > 0; d >>= 1) {
    if (t < d) ls[t] += ls[t + d];
    __syncthreads();
  }
  if (t == 0) bsum[blockIdx.x] = ls[0];
}

__global__ __launch_bounds__(512) void k_scan2(int* __restrict__ bsum, int* __restrict__ off) {
  __shared__ int ls[512];
  int t = threadIdx.x;
  ls[t] = (t < NB_SCAN) ? bsum[t] : 0;
  __syncthreads();
  for (int d = 1; d < 512; d <<= 1) {
    int v = 0;
    if (t >= d) v = ls[t - d];
    __syncthreads();
    ls[t] += v;
    __syncthreads();
  }
  if (t < NB_SCAN) bsum[t] = (t == 0) ? 0 : ls[t - 1];
  if (t == 511) off[NN] = ls[NB_SCAN - 1];
}

__global__ __launch_bounds__(256) void k_scan3(const int* __restrict__ deg, const int* __restrict__ bsum,
                                               int* __restrict__ off) {
  __shared__ int ls[256];
  int t = threadIdx.x;
  int i = blockIdx.x * 256 + t;
  int v = (i < NN) ? deg[i] : 0;
  ls[t] = v;
  __syncthreads();
  for (int d = 1; d < 256; d <<= 1) {
    int u = 0;
    if (t >= d) u = ls[t - d];
    __syncthreads();
    ls[t] += u;
    __syncthreads();
  }
  if (i < NN) off[i] = bsum[blockIdx.x] + ls[t] - v;
}

// ---------------- CSR fill: src only (norm folded into h2) ----------------
__global__ __launch_bounds__(256) void k_fill(const int* __restrict__ ei, const int* __restrict__ off,
                                              int* __restrict__ cur, u32* __restrict__ csrc) {
  int e = blockIdx.x * 256 + threadIdx.x;
  if (e >= NE) return;
  int s = ei[e], d = ei[NE + e];
  int pos = off[d] + atomicAdd(&cur[d], 1);
  csrc[pos] = (u32)s;
}

// ---------------- graph start offsets ----------------
__global__ __launch_bounds__(256) void k_goff(const int* __restrict__ batch, int* __restrict__ goff) {
  int g = blockIdx.x * 256 + threadIdx.x;
  if (g > NG) return;
  int lo = 0, hi = NN;
  while (lo < hi) { int mid = (lo + hi) >> 1; if (batch[mid] < g) lo = mid + 1; else hi = mid; }
  goff[g] = lo;
}

// ---------------- W fp32 [k][n] -> Wt bf16 [n][k] ----------------
__global__ __launch_bounds__(128) void k_wprep(const float* __restrict__ W, u16* __restrict__ Wt) {
  int n = blockIdx.x, k = threadIdx.x;
  Wt[(size_t)n * HID + k] = bf16_of(W[(size_t)k * HID + n]);
}

// ---------------- MFMA GEMM: h2[r] = dinv[r] * (f(A[r]) @ W)  (f = BN+ReLU or identity) ----------------
// block 256 (4 waves), tile 128 rows x 128 cols, K=128 in 4 chunks of 32, bf16 MFMA 16x16x32
__global__ __launch_bounds__(256) void k_gemm(const float* __restrict__ A, const u16* __restrict__ Wt,
                                              const float* __restrict__ scale, const float* __restrict__ shift,
                                              const float* __restrict__ dinv, u16* __restrict__ H) {
  __shared__ u16 Ct[128][128];                      // 32 KB; first 16 KB aliased as At/Bt during K-loop
  u16 (*At)[32] = (u16 (*)[32])(&Ct[0][0]);         // [row][k] bf16
  u16 (*Bt)[32] = (u16 (*)[32])(&Ct[32][0]);        // [n][k] bf16

  int t = threadIdx.x;
  int w = t >> 6, l = t & 63;
  int quad = l >> 4, lid = l & 15;
  int row0 = blockIdx.x * 128;

  f32x4 acc[2][8];
#pragma unroll
  for (int mt = 0; mt < 2; ++mt)
#pragma unroll
    for (int nt = 0; nt < 8; ++nt) acc[mt][nt] = (f32x4){0.f, 0.f, 0.f, 0.f};

  int ar = t >> 1;
  int ac = (t & 1) << 4;  // 0 or 16
  int grow = row0 + ar;
  bool aok = grow < NN;

  for (int k0 = 0; k0 < HID; k0 += 32) {
    // ---- stage A (fp32 -> BN/ReLU -> bf16) ----
    float4 f0 = {0, 0, 0, 0}, f1 = {0, 0, 0, 0}, f2 = {0, 0, 0, 0}, f3 = {0, 0, 0, 0};
    if (aok) {
      const float4* ap = (const float4*)(A + (size_t)grow * HID + k0 + ac);
      f0 = ap[0]; f1 = ap[1]; f2 = ap[2]; f3 = ap[3];
    }
    if (scale) {
      const float4* scp = (const float4*)(scale + k0 + ac);
      const float4* shp = (const float4*)(shift + k0 + ac);
      float4 s0 = scp[0], s1 = scp[1], s2 = scp[2], s3 = scp[3];
      float4 h0 = shp[0], h1 = shp[1], h2 = shp[2], h3 = shp[3];
      f0.x = fmaxf(fmaf(f0.x, s0.x, h0.x), 0.f); f0.y = fmaxf(fmaf(f0.y, s0.y, h0.y), 0.f);
      f0.z = fmaxf(fmaf(f0.z, s0.z, h0.z), 0.f); f0.w = fmaxf(fmaf(f0.w, s0.w, h0.w), 0.f);
      f1.x = fmaxf(fmaf(f1.x, s1.x, h1.x), 0.f); f1.y = fmaxf(fmaf(f1.y, s1.y, h1.y), 0.f);
      f1.z = fmaxf(fmaf(f1.z, s1.z, h1.z), 0.f); f1.w = fmaxf(fmaf(f1.w, s1.w, h1.w), 0.f);
      f2.x = fmaxf(fmaf(f2.x, s2.x, h2.x), 0.f); f2.y = fmaxf(fmaf(f2.y, s2.y, h2.y), 0.f);
      f2.z = fmaxf(fmaf(f2.z, s2.z, h2.z), 0.f); f2.w = fmaxf(fmaf(f2.w, s2.w, h2.w), 0.f);
      f3.x = fmaxf(fmaf(f3.x, s3.x, h3.x), 0.f); f3.y = fmaxf(fmaf(f3.y, s3.y, h3.y), 0.f);
      f3.z = fmaxf(fmaf(f3.z, s3.z, h3.z), 0.f); f3.w = fmaxf(fmaf(f3.w, s3.w, h3.w), 0.f);
    }
    uint4 q0, q1;
    q0.x = pack_bf16(f0.x, f0.y); q0.y = pack_bf16(f0.z, f0.w);
    q0.z = pack_bf16(f1.x, f1.y); q0.w = pack_bf16(f1.z, f1.w);
    q1.x = pack_bf16(f2.x, f2.y); q1.y = pack_bf16(f2.z, f2.w);
    q1.z = pack_bf16(f3.x, f3.y); q1.w = pack_bf16(f3.z, f3.w);
    *(uint4*)&At[ar][ac] = q0;
    *(uint4*)&At[ar][ac + 8] = q1;
    // ---- stage B (bf16 copy from Wt) ----
    const u16* wp = Wt + (size_t)(t >> 1) * HID + k0 + ac;
    *(uint4*)&Bt[t >> 1][ac]     = ((const uint4*)wp)[0];
    *(uint4*)&Bt[t >> 1][ac + 8] = ((const uint4*)wp)[1];
    __syncthreads();
    // ---- fragments + MFMA ----
    short8 a0 = *(const short8*)&At[(w << 5) + lid][quad << 3];
    short8 a1 = *(const short8*)&At[(w << 5) + 16 + lid][quad << 3];
#pragma unroll
    for (int nt = 0; nt < 8; ++nt) {
      short8 b = *(const short8*)&Bt[(nt << 4) + lid][quad << 3];
      acc[0][nt] = __builtin_amdgcn_mfma_f32_16x16x32_bf16(a0, b, acc[0][nt], 0, 0, 0);
      acc[1][nt] = __builtin_amdgcn_mfma_f32_16x16x32_bf16(a1, b, acc[1][nt], 0, 0, 0);
    }
    __syncthreads();
  }

  // ---- epilogue: scale by dinv, pack bf16 into Ct, coalesced copy out ----
  int valid = min(128, NN - row0);
#pragma unroll
  for (int mt = 0; mt < 2; ++mt) {
#pragma unroll
    for (int r = 0; r < 4; ++r) {
      int rl = (w << 5) + (mt << 4) + (quad << 2) + r;
      float dv = (rl < valid) ? dinv[row0 + rl] : 0.f;
#pragma unroll
      for (int nt = 0; nt < 8; ++nt) {
        Ct[rl][(nt << 4) + lid] = bf16_of(acc[mt][nt][r] * dv);
      }
    }
  }
  __syncthreads();
  u16* Hb = H + (size_t)row0 * HID;
  int tot = valid << 4;  // 16 uint4 per row
  for (int idx = t; idx < tot; idx += 256) {
    ((uint4*)Hb)[idx] = ((const uint4*)Ct)[idx];
  }
}

// ---------------- pull aggregation: wave = node, pure adds, scale by dinv at end ----------------
__global__ __launch_bounds__(256) void k_agg(const u16* __restrict__ h2, const int* __restrict__ off,
                                             const u32* __restrict__ csrc, const float* __restrict__ dinv,
                                             float* __restrict__ agg) {
  int node = (int)((blockIdx.x * 256 + threadIdx.x) >> 6);
  int lane = threadIdx.x & 63;
  if (node >= NN) return;
  int beg = off[node], end = off[node + 1];
  u32 us = ((const u32*)(h2 + (size_t)node * HID))[lane];
  float ax = bf_lo(us), ay = bf_hi(us);
  int e = beg;
  for (; e + 4 <= end; e += 4) {
    u32 s0 = csrc[e], s1 = csrc[e + 1], s2 = csrc[e + 2], s3 = csrc[e + 3];
    u32 v0 = ((const u32*)(h2 + (size_t)s0 * HID))[lane];
    u32 v1 = ((const u32*)(h2 + (size_t)s1 * HID))[lane];
    u32 v2 = ((const u32*)(h2 + (size_t)s2 * HID))[lane];
    u32 v3 = ((const u32*)(h2 + (size_t)s3 * HID))[lane];
    ax += bf_lo(v0) + bf_lo(v1) + bf_lo(v2) + bf_lo(v3);
    ay += bf_hi(v0) + bf_hi(v1) + bf_hi(v2) + bf_hi(v3);
  }
  for (; e < end; ++e) {
    u32 v = ((const u32*)(h2 + (size_t)csrc[e] * HID))[lane];
    ax += bf_lo(v);
    ay += bf_hi(v);
  }
  float di = dinv[node];
  float2 o; o.x = ax * di; o.y = ay * di;
  ((float2*)(agg + (size_t)node * HID))[lane] = o;
}

// ---------------- BN statistics ----------------
__global__ __launch_bounds__(256) void k_bnstats(const float* __restrict__ X, float* __restrict__ buf) {
  __shared__ float ls[256], lss[256];
  int t = threadIdx.x;
  int col = t & 127, half = t >> 7;
  int rbeg = blockIdx.x * 256, rend = min(rbeg + 256, NN);
  float s = 0.f, ss = 0.f;
  for (int r = rbeg + half; r < rend; r += 2) {
    float v = X[(size_t)r * HID + col];
    s += v; ss = fmaf(v, v, ss);
  }
  ls[t] = s; lss[t] = ss;
  __syncthreads();
  if (t < 128) {
    s = ls[t] + ls[t + 128];
    ss = lss[t] + lss[t + 128];
    atomicAdd(&buf[col], s);
    atomicAdd(&buf[HID + col], ss);
  }
}

__global__ void k_bnfinal(float* __restrict__ buf, const float* __restrict__ g, const float* __restrict__ be) {
  int j = threadIdx.x;
  const float invN = 1.0f / (float)NN;
  float mu = buf[j] * invN;
  float var = buf[HID + j] * invN - mu * mu;
  float sc = g[j] * rsqrtf(var + BN_EPS);
  buf[j] = sc;
  buf[HID + j] = be[j] - mu * sc;
}

// ---------------- mean pool (layer-3 BN+ReLU fused) ----------------
__global__ __launch_bounds__(256) void k_pool(const float* __restrict__ agg, const float* __restrict__ bn,
                                              const int* __restrict__ goff, float* __restrict__ pooled) {
  int g = (int)((blockIdx.x * 256 + threadIdx.x) >> 6);
  int lane = threadIdx.x & 63;
  if (g >= NG) return;
  int beg = goff[g], end = goff[g + 1];
  float2 sc = ((const float2*)bn)[lane];
  float2 sh = ((const float2*)(bn + HID))[lane];
  float2 acc; acc.x = 0.f; acc.y = 0.f;
  for (int r = beg; r < end; ++r) {
    float2 v = ((const float2*)(agg + (size_t)r * HID))[lane];
    acc.x += fmaxf(fmaf(v.x, sc.x, sh.x), 0.f);
    acc.y += fmaxf(fmaf(v.y, sc.y, sh.y), 0.f);
  }
  float inv = 1.0f / fmaxf((float)(end - beg), 1.0f);
  acc.x *= inv; acc.y *= inv;
  ((float2*)(pooled + (size_t)g * HID))[lane] = acc;
}

// ---------------- final FC ----------------
__global__ __launch_bounds__(256) void k_fc(const float* __restrict__ pooled, const float* __restrict__ fcW,
                                            const float* __restrict__ fcb, float* __restrict__ out) {
  int t = threadIdx.x;
  int c = t & 63;
  int g = blockIdx.x * 4 + (t >> 6);
  if (g >= NG) return;
  const float* p = pooled + (size_t)g * HID;
  float acc = fcb[c];
#pragma unroll 8
  for (int k = 0; k < HID; ++k) acc = fmaf(p[k], fcW[(size_t)k * ODIM + c], acc);
  out[(size_t)g * ODIM + c] = acc;
}

extern "C" void kernel_launch(void* const* d_in, const int* in_sizes, int n_in,
                              void* d_out, int out_size, void* d_ws, size_t ws_size,
                              hipStream_t stream) {
  const float* x     = (const float*)d_in[0];
  const int*   ei    = (const int*)d_in[1];
  const int*   batch = (const int*)d_in[2];
  const float* W1    = (const float*)d_in[3];
  // b1/b2/b3 (d_in[4,8,12]) skipped: per-feature bias cancels exactly in the following BN
  const float* g1    = (const float*)d_in[5];
  const float* be1   = (const float*)d_in[6];
  const float* W2    = (const float*)d_in[7];
  const float* g2    = (const float*)d_in[9];
  const float* be2   = (const float*)d_in[10];
  const float* W3    = (const float*)d_in[11];
  const float* g3    = (const float*)d_in[13];
  const float* be3   = (const float*)d_in[14];
  const float* fcW   = (const float*)d_in[15];
  const float* fcb   = (const float*)d_in[16];
  float* out = (float*)d_out;

  char* p = (char*)d_ws;
  auto alloc = [&](size_t bytes) { char* r = p; p += (bytes + 255) & ~(size_t)255; return r; };
  int*   deg    = (int*)alloc((size_t)NN * 4);
  int*   cur    = (int*)alloc((size_t)NN * 4);
  float* bnb    = (float*)alloc(3 * 256 * 4);
  size_t zbytes = (size_t)(p - (char*)d_ws);
  int*   off    = (int*)alloc((size_t)(NN + 1) * 4);
  int*   bsum   = (int*)alloc((size_t)NB_SCAN * 4);
  float* dinv   = (float*)alloc((size_t)NN * 4);
  u32*   csrc   = (u32*)alloc((size_t)NE * 4);
  int*   goff   = (int*)alloc((size_t)(NG + 1) * 4);
  u16*   Wt1    = (u16*)alloc((size_t)HID * HID * 2);
  u16*   Wt2    = (u16*)alloc((size_t)HID * HID * 2);
  u16*   Wt3    = (u16*)alloc((size_t)HID * HID * 2);
  u16*   h2     = (u16*)alloc((size_t)NN * HID * 2);
  float* agg    = (float*)alloc((size_t)NN * HID * 4);
  float* pooled = (float*)alloc((size_t)NG * HID * 4);

  hipMemsetAsync(d_ws, 0, zbytes, stream);

  const int EB = NE / 256;               // 6250
  const int NB = (NN + 255) / 256;       // 391
  const int GB = (NN + 127) / 128;       // 782 gemm blocks
  const int AGB = NN / 4;                // 25000

  k_deg<<<EB, 256, 0, stream>>>(ei, deg);
  k_dinv<<<NB, 256, 0, stream>>>(deg, dinv);
  k_scan1<<<NB_SCAN, 256, 0, stream>>>(deg, bsum);
  k_scan2<<<1, 512, 0, stream>>>(bsum, off);
  k_scan3<<<NB_SCAN, 256, 0, stream>>>(deg, bsum, off);
  k_fill<<<EB, 256, 0, stream>>>(ei, off, cur, csrc);
  k_goff<<<(NG + 1 + 255) / 256, 256, 0, stream>>>(batch, goff);
  k_wprep<<<HID, HID, 0, stream>>>(W1, Wt1);
  k_wprep<<<HID, HID, 0, stream>>>(W2, Wt2);
  k_wprep<<<HID, HID, 0, stream>>>(W3, Wt3);

  // layer 1
  k_gemm<<<GB, 256, 0, stream>>>(x, Wt1, nullptr, nullptr, dinv, h2);
  k_agg<<<AGB, 256, 0, stream>>>(h2, off, csrc, dinv, agg);
  k_bnstats<<<NB, 256, 0, stream>>>(agg, bnb);
  k_bnfinal<<<1, 128, 0, stream>>>(bnb, g1, be1);
  // layer 2
  k_gemm<<<GB, 256, 0, stream>>>(agg, Wt2, bnb, bnb + HID, dinv, h2);
  k_agg<<<AGB, 256, 0, stream>>>(h2, off, csrc, dinv, agg);
  k_bnstats<<<NB, 256, 0, stream>>>(agg, bnb + 256);
  k_bnfinal<<<1, 128, 0, stream>>>(bnb + 256, g2, be2);
  // layer 3
  k_gemm<<<GB, 256, 0, stream>>>(agg, Wt3, bnb + 256, bnb + 256 + HID, dinv, h2);
  k_agg<<<AGB, 256, 0, stream>>>(h2, off, csrc, dinv, agg);
  k_bnstats<<<NB, 256, 0, stream>>>(agg, bnb + 512);
  k_bnfinal<<<1, 128, 0, stream>>>(bnb + 512, g3, be3);
  // pool + FC
  k_pool<<<(NG * 64) / 256, 256, 0, stream>>>(agg, bnb + 512, goff, pooled);
  k_fc<<<NG / 4, 256, 0, stream>>>(pooled, fcW, fcb, out);
}